// Round 7
// baseline (257.609 us; speedup 1.0000x reference)
//
#include <hip/hip_runtime.h>
#include <hip/hip_bf16.h>

#define Tn 512
#define Bn 512
#define Kn 128

typedef __bf16 bf16_t;
typedef __bf16 bf16x8 __attribute__((ext_vector_type(8)));
typedef float f32x4 __attribute__((ext_vector_type(4)));
typedef unsigned int u32;
typedef u32 u32x4 __attribute__((ext_vector_type(4)));

__device__ __forceinline__ u32 pack2bf(float a, float b) {
    bf16_t ha = (bf16_t)a, hb = (bf16_t)b;
    u32 ua = (u32)__builtin_bit_cast(unsigned short, ha);
    u32 ub = (u32)__builtin_bit_cast(unsigned short, hb);
    return ua | (ub << 16);
}

// ---------------- expem: X[t,b,k] = bf16(exp(em[t,b,k])) ----------------
__global__ __launch_bounds__(256)
void crf_expem(const float* __restrict__ em, u32* __restrict__ X)
{
    const size_t N = (size_t)Tn * Bn * Kn;
    const size_t nth = (size_t)gridDim.x * blockDim.x;
    for (size_t base = ((size_t)blockIdx.x * blockDim.x + threadIdx.x) * 8; base < N;
         base += nth * 8) {
        const f32x4 a = *reinterpret_cast<const f32x4*>(em + base);
        const f32x4 b = *reinterpret_cast<const f32x4*>(em + base + 4);
        u32x4 w;
        w[0] = pack2bf(__expf(a[0]), __expf(a[1]));
        w[1] = pack2bf(__expf(a[2]), __expf(a[3]));
        w[2] = pack2bf(__expf(b[0]), __expf(b[1]));
        w[3] = pack2bf(__expf(b[2]), __expf(b[3]));
        *reinterpret_cast<u32x4*>(X + base / 2) = w;
    }
}

// ---------------- prep: E A-fragment build + numerator + out zeroing ----------------
// A-frag image: idx = (((dir*8 + m)*4 + ks)*64 + l)*8 + e
//   lane roles: c=l&15, g=l>>4;  k = 32*ks + 8*g + e
//   row j = J(m,c) = 32*(m>>1) + 4*(m&1) + 8*(c>>2) + (c&3)
//   dir 0 (fwd): A[j][k] = exp(trans[k][j]);  dir 1 (bwd): A[j][k] = exp(trans[j][k])
// J chosen so D's per-lane output IS the next step's B-frag layout (verified r1-r6).
__global__ void crf_prep(const float* __restrict__ em, const int* __restrict__ tags,
                         const int* __restrict__ mask, const float* __restrict__ startT,
                         const float* __restrict__ endT, const float* __restrict__ trans,
                         bf16_t* __restrict__ frags, float* __restrict__ num,
                         float* __restrict__ out)
{
    const int bid = blockIdx.x;
    const int tid = threadIdx.x;
    if (bid == Bn) {
        if (tid == 0) out[0] = 0.f;
        for (int idx = tid; idx < 2*8*4*64*8; idx += blockDim.x) {
            const int e   = idx & 7;
            const int l   = (idx >> 3) & 63;
            const int ks  = (idx >> 9) & 3;
            const int m   = (idx >> 11) & 7;
            const int dir = (idx >> 14) & 1;
            const int c = l & 15, g = l >> 4;
            const int k = 32*ks + 8*g + e;
            const int j = 32*(m >> 1) + 4*(m & 1) + 8*(c >> 2) + (c & 3);
            const float v = (dir == 0) ? trans[k*Kn + j] : trans[j*Kn + k];
            frags[idx] = (bf16_t)__expf(v);
        }
        return;
    }
    const int b = bid;
    float s = 0.f;
    int cnt = 0;
    for (int t = tid; t < Tn; t += blockDim.x) {
        const int mk = mask[t*Bn + b];
        cnt += (mk != 0);
        if (t >= 1 && mk != 0) {
            const int tp = tags[(t-1)*Bn + b];
            const int tc = tags[t*Bn + b];
            s += trans[tp*Kn + tc] + em[(size_t)t*Bn*Kn + (size_t)b*Kn + tc];
        }
    }
    __shared__ float sred[128];
    __shared__ int   cred[128];
    sred[tid] = s; cred[tid] = cnt;
    __syncthreads();
    for (int off = 64; off > 0; off >>= 1) {
        if (tid < off) { sred[tid] += sred[tid+off]; cred[tid] += cred[tid+off]; }
        __syncthreads();
    }
    if (tid == 0) {
        const int t0tag = tags[b];
        const float n0 = startT[t0tag] + em[(size_t)b*Kn + t0tag];
        int seq_end = cred[0] - 1;
        if (seq_end < 0) seq_end = 0;
        const int lastTag = tags[seq_end*Bn + b];
        num[b] = n0 + sred[0] + endT[lastTag];
    }
}

// ---------------- main: 4 chains x 4-wave j-split per block (16 waves) ----------------
// 16 blocks x 1024 threads. Blocks 0-7: fwd chains, 8-15: bwd (M uniform per block so
// the shared s_barrier trip count is identical for all 16 waves -> no deadlock).
// Chain ch = tid>>8 (4 per block, 8KB LDS exchange each); wave w = (tid>>6)&3 owns
// m-tiles {2w,2w+1} -> produces state k-slice ks=w. 4 waves/SIMD hide each other's
// ds_read/MFMA dependency stalls (TLP); VALU issue port becomes the floor.
template<int PRE>
__global__ __launch_bounds__(1024, 1)
void crf_main(const float* __restrict__ em, const u32* __restrict__ Xp,
              const int* __restrict__ maskp,
              const float* __restrict__ startT, const float* __restrict__ endT,
              const bf16_t* __restrict__ frags,
              float* __restrict__ vws, float* __restrict__ Cws)
{
    const int bid = blockIdx.x;          // 16 blocks
    const int dir = bid >> 3;            // 0-7 fwd, 8-15 bwd
    const int tid = threadIdx.x;
    const int ch  = tid >> 8;            // chain within block
    const int grp = (bid & 7) * 4 + ch;  // batch group 0..31
    const int b0  = grp * 16;
    const int w   = (tid >> 6) & 3;      // slice wave: m-tiles {2w,2w+1}, k-slice ks=w
    const int l   = tid & 63;
    const int c = l & 15, g = l >> 4;
    const int batch = b0 + c;

    __shared__ __align__(16) u32x4 exchg[4][2][4][64];   // [chain][parity][slice][lane]

    // resident E fragments for own m-tiles
    bf16x8 af[2][4];
    {
        const bf16_t* fb = frags + (size_t)dir * 16384;
        #pragma unroll
        for (int i = 0; i < 2; ++i)
            #pragma unroll
            for (int ks = 0; ks < 4; ++ks)
                af[i][ks] = *reinterpret_cast<const bf16x8*>(fb + (((2*w + i)*4 + ks)*64 + l)*8);
    }

    // init own state slice (+ bwd f32 state)
    f32x4 up[2];
    float Cacc = 0.f;
    {
        const float* sv = dir ? endT : startT;
        const int t0 = dir ? 511 : 0;
        const float* p0 = em + ((size_t)t0*Bn + batch)*Kn + 8*g;
        u32x4 own;
        #pragma unroll
        for (int i = 0; i < 2; ++i) {
            const int off = 32*w + 4*i;
            const f32x4 e4 = *reinterpret_cast<const f32x4*>(p0 + off);
            const f32x4 s4 = *reinterpret_cast<const f32x4*>(sv + 8*g + off);
            f32x4 y;
            #pragma unroll
            for (int r = 0; r < 4; ++r) {
                y[r]      = __expf(s4[r] + e4[r]);
                up[i][r]  = __expf(s4[r]);
            }
            own[2*i]     = pack2bf(y[0], y[1]);
            own[2*i + 1] = pack2bf(y[2], y[3]);
        }
        exchg[ch][1][w][l] = own;   // iter m=1 reads parity 1
    }

    const int M = 256 - dir;

    // x tile per wave: own 8 bf16 (1 dwordx4) or 8 f32 (PRE=0)
    u32x4 xA, xB;
    f32x4 eA[2], eB[2];
    int mkA, mkB;

    auto load_tile = [&](u32x4& xd, f32x4 (&ed)[2], int& mk, int midx) {
        const int t_ = dir ? (511 - midx) : midx;
        const int tm = dir ? (512 - midx) : midx;
        if (PRE) {
            const u32* wp = Xp + (((size_t)t_*Bn + batch)*Kn >> 1) + 4*g + 16*w;
            xd = *reinterpret_cast<const u32x4*>(wp);
        } else {
            const float* p = em + ((size_t)t_*Bn + batch)*Kn + 8*g + 32*w;
            ed[0] = *reinterpret_cast<const f32x4*>(p);
            ed[1] = *reinterpret_cast<const f32x4*>(p + 4);
        }
        mk = maskp[(size_t)tm*Bn + batch];
    };

    auto iter = [&](u32x4& xcur, f32x4 (&ecur)[2], int& mkcur, int m, bool rs, int par) {
        // release own write of previous step, sync, then read full state
        asm volatile("s_waitcnt lgkmcnt(0)" ::: "memory");
        __builtin_amdgcn_s_barrier();
        __builtin_amdgcn_sched_barrier(0);

        u32x4 bs[4];
        bs[0] = exchg[ch][par][0][l];
        bs[1] = exchg[ch][par][1][l];
        bs[2] = exchg[ch][par][2][l];
        bs[3] = exchg[ch][par][3][l];
        const u32x4 ownold = exchg[ch][par][w][l];   // fwd mask-keep source

        f32x4 acc[2];
        acc[0] = f32x4{0.f, 0.f, 0.f, 0.f};
        acc[1] = f32x4{0.f, 0.f, 0.f, 0.f};
        #pragma unroll
        for (int ks = 0; ks < 4; ++ks) {
            const bf16x8 bf = __builtin_bit_cast(bf16x8, bs[ks]);
            acc[0] = __builtin_amdgcn_mfma_f32_16x16x32_bf16(af[0][ks], bf, acc[0], 0, 0, 0);
            acc[1] = __builtin_amdgcn_mfma_f32_16x16x32_bf16(af[1][ks], bf, acc[1], 0, 0, 0);
        }

        const bool mk = (mkcur != 0);
        float sc = 1.f, klog = 0.f;
        if (rs) {   // exact pow-2 rescale; exponent of k=0 component of batch c
            int ex = (int)((bs[0][0] >> 7) & 0xFF) - 127;
            ex = __shfl(ex, c, 64);
            sc = __uint_as_float((u32)((127 - ex) & 0xFF) << 23);
            klog = (float)ex * 0.6931471805599453f;
        }

        auto xfac = [&](int i, int t4) -> float {
            if (PRE) {
                const u32 wv = xcur[2*i + (t4 >> 1)];
                return __uint_as_float((t4 & 1) ? (wv & 0xffff0000u) : (wv << 16));
            }
            return __expf(ecur[i][t4]);
        };

        u32x4 nw;
        if (dir == 0) {  // fwd: v_t = (v@E)*x_t if mask else v
            #pragma unroll
            for (int i = 0; i < 2; ++i) {
                f32x4 y;
                #pragma unroll
                for (int t4 = 0; t4 < 4; ++t4) {
                    float a = acc[i][t4];
                    if (rs) a *= sc;
                    y[t4] = a * xfac(i, t4);
                }
                nw[2*i]     = pack2bf(y[0], y[1]);
                nw[2*i + 1] = pack2bf(y[2], y[3]);
            }
            #pragma unroll
            for (int j = 0; j < 4; ++j) nw[j] = mk ? nw[j] : ownold[j];
            if (rs && mk) Cacc += klog;
        } else {  // bwd: u = select(E@B, u); scale both branches; B = u*x_t
            #pragma unroll
            for (int i = 0; i < 2; ++i) {
                f32x4 y;
                #pragma unroll
                for (int t4 = 0; t4 < 4; ++t4) {
                    float un = mk ? acc[i][t4] : up[i][t4];
                    if (rs) un *= sc;
                    up[i][t4] = un;
                    y[t4] = un * xfac(i, t4);
                }
                nw[2*i]     = pack2bf(y[0], y[1]);
                nw[2*i + 1] = pack2bf(y[2], y[3]);
            }
            if (rs) Cacc += klog;
        }

        exchg[ch][par ^ 1][w][l] = nw;      // next step's state slice

        int ms = m + 2; if (ms > M) ms = M; // clamp keeps vmem count invariant
        load_tile(xcur, ecur, mkcur, ms);
        __builtin_amdgcn_sched_barrier(0xF); // ALU/VALU/SALU/MFMA may cross; VMEM+DS pinned
    };

    load_tile(xA, eA, mkA, 1);
    load_tile(xB, eB, mkB, 2);
    __builtin_amdgcn_sched_barrier(0xF);

    int m = 1;
    for (; m + 3 <= M; m += 4) {       // rs static: only (m+3)%4==0 rescales; par static
        iter(xA, eA, mkA, m,     false, 1);
        iter(xB, eB, mkB, m + 1, false, 0);
        iter(xA, eA, mkA, m + 2, false, 1);
        iter(xB, eB, mkB, m + 3, true,  0);
    }
    for (; m <= M; ++m) {              // bwd tail m=253..255 (never a rescale step)
        if (m & 1) iter(xA, eA, mkA, m, false, m & 1);
        else       iter(xB, eB, mkB, m, false, m & 1);
    }

    // final own state: fwd from LDS (own last-written slice), bwd from f32 up
    asm volatile("s_waitcnt lgkmcnt(0)" ::: "memory");
    const u32x4 fin = exchg[ch][(M + 1) & 1][w][l];
    float* vrow = vws + ((size_t)(dir*Bn + batch))*Kn + 8*g;
    #pragma unroll
    for (int i = 0; i < 2; ++i) {
        const int off = 32*w + 4*i;
        #pragma unroll
        for (int r = 0; r < 4; ++r) {
            float val;
            if (dir) {
                val = up[i][r];
            } else {
                const u32 wv = fin[2*i + (r >> 1)];
                const u32 h  = (r & 1) ? (wv >> 16) : (wv & 0xffffu);
                val = __uint_as_float(h << 16);
            }
            vrow[off + r] = val;
        }
    }
    if (w == 0 && g == 0) Cws[dir*Bn + batch] = Cacc;
}

// ---------------- combine: den = Cf + Cb + log(a_256 . u_256); out += num - den ----------------
__global__ void crf_combine(const float* __restrict__ vws, const float* __restrict__ Cws,
                            const float* __restrict__ num, float* __restrict__ out)
{
    const int b = blockIdx.x;
    const int tid = threadIdx.x;
    const float p = vws[(size_t)b*Kn + tid] * vws[(size_t)(Bn + b)*Kn + tid];
    __shared__ float red[128];
    red[tid] = p;
    __syncthreads();
    for (int off = 64; off > 0; off >>= 1) {
        if (tid < off) red[tid] += red[tid + off];
        __syncthreads();
    }
    if (tid == 0) {
        const float den = Cws[b] + Cws[Bn + b] + logf(red[0]);
        atomicAdd(out, num[b] - den);
    }
}

extern "C" void kernel_launch(void* const* d_in, const int* in_sizes, int n_in,
                              void* d_out, int out_size, void* d_ws, size_t ws_size,
                              hipStream_t stream)
{
    const float* em     = (const float*)d_in[0];
    const int*   tags   = (const int*)d_in[1];
    const int*   mask   = (const int*)d_in[2];
    const float* startT = (const float*)d_in[3];
    const float* endT   = (const float*)d_in[4];
    const float* trans  = (const float*)d_in[5];

    const size_t XBYTES = (size_t)Tn * Bn * Kn * 2;         // 33.5 MB
    const size_t SMALL  = 65536 + 2048 + 4096 + 524288;     // frags+num+Cws+vws
    const bool pre = (ws_size >= XBYTES + SMALL);

    char* ws = (char*)d_ws;
    u32*  X  = (u32*)ws;                                    // PRE path only
    char* base = pre ? (ws + XBYTES) : ws;
    bf16_t* frags = (bf16_t*)base;
    float*  num   = (float*)(base + 65536);
    float*  Cws   = (float*)(base + 65536 + 2048);
    float*  vws   = (float*)(base + 65536 + 2048 + 4096);
    float*  out   = (float*)d_out;

    hipLaunchKernelGGL(crf_prep, dim3(Bn + 1), dim3(128), 0, stream,
                       em, tags, mask, startT, endT, trans, frags, num, out);
    if (pre) {
        hipLaunchKernelGGL(crf_expem, dim3(4096), dim3(256), 0, stream, em, X);
        hipLaunchKernelGGL((crf_main<1>), dim3(16), dim3(1024), 0, stream,
                           em, X, mask, startT, endT, frags, vws, Cws);
    } else {
        hipLaunchKernelGGL((crf_main<0>), dim3(16), dim3(1024), 0, stream,
                           em, X, mask, startT, endT, frags, vws, Cws);
    }
    hipLaunchKernelGGL(crf_combine, dim3(Bn), dim3(128), 0, stream,
                       vws, Cws, num, out);
}

// Round 8
// 169.788 us; speedup vs baseline: 1.5172x; 1.5172x over previous
//
#include <hip/hip_runtime.h>
#include <hip/hip_bf16.h>

#define Tn 512
#define Bn 512
#define Kn 128

typedef __bf16 bf16_t;
typedef __bf16 bf16x8 __attribute__((ext_vector_type(8)));
typedef float f32x4 __attribute__((ext_vector_type(4)));
typedef unsigned int u32;
typedef u32 u32x2 __attribute__((ext_vector_type(2)));
typedef u32 u32x4 __attribute__((ext_vector_type(4)));

__device__ __forceinline__ u32 pack2bf(float a, float b) {
    bf16_t ha = (bf16_t)a, hb = (bf16_t)b;
    u32 ua = (u32)__builtin_bit_cast(unsigned short, ha);
    u32 ub = (u32)__builtin_bit_cast(unsigned short, hb);
    return ua | (ub << 16);
}

// ---------------- expem: X[t,b,k] = bf16(exp(em[t,b,k])) ----------------
__global__ __launch_bounds__(256)
void crf_expem(const float* __restrict__ em, u32* __restrict__ X)
{
    const size_t N = (size_t)Tn * Bn * Kn;
    const size_t nth = (size_t)gridDim.x * blockDim.x;
    for (size_t base = ((size_t)blockIdx.x * blockDim.x + threadIdx.x) * 8; base < N;
         base += nth * 8) {
        const f32x4 a = *reinterpret_cast<const f32x4*>(em + base);
        const f32x4 b = *reinterpret_cast<const f32x4*>(em + base + 4);
        u32x4 w;
        w[0] = pack2bf(__expf(a[0]), __expf(a[1]));
        w[1] = pack2bf(__expf(a[2]), __expf(a[3]));
        w[2] = pack2bf(__expf(b[0]), __expf(b[1]));
        w[3] = pack2bf(__expf(b[2]), __expf(b[3]));
        *reinterpret_cast<u32x4*>(X + base / 2) = w;
    }
}

// ---------------- prep: E A-fragment build + numerator + out zeroing ----------------
// A-frag image: idx = (((dir*8 + m)*4 + ks)*64 + l)*8 + e
//   lane roles: c=l&15, g=l>>4;  k = 32*ks + 8*g + e
//   row j = J(m,c) = 32*(m>>1) + 4*(m&1) + 8*(c>>2) + (c&3)
//   dir 0 (fwd): A[j][k] = exp(trans[k][j]);  dir 1 (bwd): A[j][k] = exp(trans[j][k])
// J chosen so D's per-lane output IS the next step's B-frag layout (verified r1-r7).
__global__ void crf_prep(const float* __restrict__ em, const int* __restrict__ tags,
                         const int* __restrict__ mask, const float* __restrict__ startT,
                         const float* __restrict__ endT, const float* __restrict__ trans,
                         bf16_t* __restrict__ frags, float* __restrict__ num,
                         float* __restrict__ out)
{
    const int bid = blockIdx.x;
    const int tid = threadIdx.x;
    if (bid == Bn) {
        if (tid == 0) out[0] = 0.f;
        for (int idx = tid; idx < 2*8*4*64*8; idx += blockDim.x) {
            const int e   = idx & 7;
            const int l   = (idx >> 3) & 63;
            const int ks  = (idx >> 9) & 3;
            const int m   = (idx >> 11) & 7;
            const int dir = (idx >> 14) & 1;
            const int c = l & 15, g = l >> 4;
            const int k = 32*ks + 8*g + e;
            const int j = 32*(m >> 1) + 4*(m & 1) + 8*(c >> 2) + (c & 3);
            const float v = (dir == 0) ? trans[k*Kn + j] : trans[j*Kn + k];
            frags[idx] = (bf16_t)__expf(v);
        }
        return;
    }
    const int b = bid;
    float s = 0.f;
    int cnt = 0;
    for (int t = tid; t < Tn; t += blockDim.x) {
        const int mk = mask[t*Bn + b];
        cnt += (mk != 0);
        if (t >= 1 && mk != 0) {
            const int tp = tags[(t-1)*Bn + b];
            const int tc = tags[t*Bn + b];
            s += trans[tp*Kn + tc] + em[(size_t)t*Bn*Kn + (size_t)b*Kn + tc];
        }
    }
    __shared__ float sred[128];
    __shared__ int   cred[128];
    sred[tid] = s; cred[tid] = cnt;
    __syncthreads();
    for (int off = 64; off > 0; off >>= 1) {
        if (tid < off) { sred[tid] += sred[tid+off]; cred[tid] += cred[tid+off]; }
        __syncthreads();
    }
    if (tid == 0) {
        const int t0tag = tags[b];
        const float n0 = startT[t0tag] + em[(size_t)b*Kn + t0tag];
        int seq_end = cred[0] - 1;
        if (seq_end < 0) seq_end = 0;
        const int lastTag = tags[seq_end*Bn + b];
        num[b] = n0 + sred[0] + endT[lastTag];
    }
}

// ---------------- main: 8-wave j-split recurrence, LDS state exchange ----------------
// 64 blocks x 512 threads (8 waves = 2 waves/SIMD on 64 CUs). Wave m owns m-tile m
// (4 MFMA), produces 4 output j's per lane = half of k-slice ks=m>>1 (u32x2 b64 write).
// Full state read back as 4x ds_read_b128. One raw s_barrier per step; 2 waves/SIMD
// overlap each other's barrier/ds_read/MFMA latency. Clamp-free prefetch (all t
// in-bounds through m = M+2), incremental pointers, reg-held ownprev.
template<int PRE>
__global__ __launch_bounds__(512, 1)
void crf_main(const float* __restrict__ em, const u32* __restrict__ Xp,
              const int* __restrict__ maskp,
              const float* __restrict__ startT, const float* __restrict__ endT,
              const bf16_t* __restrict__ frags,
              float* __restrict__ vws, float* __restrict__ Cws)
{
    const int bid = blockIdx.x;          // 64 blocks
    const int dir = bid & 1;
    const int b0  = (bid >> 1) * 16;
    const int tid = threadIdx.x;
    const int mw  = tid >> 6;            // wave id = m-tile index 0..7
    const int l   = tid & 63;
    const int c = l & 15, g = l >> 4;
    const int batch = b0 + c;
    const int ksw  = mw >> 1, half = mw & 1;
    const int bj   = 32*ksw + 4*half;    // base j of own 4 outputs (plus 8g)

    __shared__ __align__(16) u32x4 exchg[2][4][64];   // [parity][slice][lane]

    // resident E fragments for own m-tile
    bf16x8 af[4];
    {
        const bf16_t* fb = frags + (size_t)dir * 16384;
        #pragma unroll
        for (int ks = 0; ks < 4; ++ks)
            af[ks] = *reinterpret_cast<const bf16x8*>(fb + ((mw*4 + ks)*64 + l)*8);
    }

    // init own state (+ bwd f32 state)
    f32x4 up;
    u32 ownprev0, ownprev1;
    float Cacc = 0.f;
    {
        const float* sv = dir ? endT : startT;
        const int t0 = dir ? 511 : 0;
        const f32x4 e4 = *reinterpret_cast<const f32x4*>(
            em + ((size_t)t0*Bn + batch)*Kn + bj + 8*g);
        const float* s4p = sv + bj + 8*g;
        f32x4 y;
        #pragma unroll
        for (int r = 0; r < 4; ++r) {
            const float s = s4p[r];
            y[r]  = __expf(s + e4[r]);
            up[r] = __expf(s);
        }
        ownprev0 = pack2bf(y[0], y[1]);
        ownprev1 = pack2bf(y[2], y[3]);
        u32* slot = reinterpret_cast<u32*>(&exchg[1][ksw][l]) + 2*half;
        u32x2 nw2 = {ownprev0, ownprev1};
        *reinterpret_cast<u32x2*>(slot) = nw2;   // iter m=1 reads parity 1
    }

    const int M = 256 - dir;

    // incremental per-buffer pointers (each advances 2 t per use; always in-bounds)
    const int xstep_pre = dir ? -(Bn*Kn)     : (Bn*Kn);       // u32 units / 2t
    const int xstep_f32 = dir ? -(2*Bn*Kn)   : (2*Bn*Kn);     // f32 units / 2t
    const int mstep     = dir ? -(2*Bn)      : (2*Bn);        // int units / 2t
    const u32 *pXA, *pXB; const float *pEA, *pEB; const int *pMA, *pMB;
    {
        const int tA  = dir ? 510 : 1, tB  = dir ? 509 : 2;
        const int tmA = dir ? 511 : 1, tmB = dir ? 510 : 2;
        pXA = Xp + (((size_t)tA*Bn + batch)*Kn >> 1) + ((bj + 8*g) >> 1);
        pXB = Xp + (((size_t)tB*Bn + batch)*Kn >> 1) + ((bj + 8*g) >> 1);
        pEA = em + ((size_t)tA*Bn + batch)*Kn + bj + 8*g;
        pEB = em + ((size_t)tB*Bn + batch)*Kn + bj + 8*g;
        pMA = maskp + (size_t)tmA*Bn + batch;
        pMB = maskp + (size_t)tmB*Bn + batch;
    }

    u32x2 xA, xB; f32x4 eA, eB; int mkA, mkB;
    auto load_tile = [&](u32x2& xd, f32x4& ed, int& mk,
                         const u32*& pX, const float*& pE, const int*& pM) {
        if (PRE) { xd = *reinterpret_cast<const u32x2*>(pX); pX += xstep_pre; }
        else     { ed = *reinterpret_cast<const f32x4*>(pE); pE += xstep_f32; }
        mk = *pM; pM += mstep;
    };

    auto iter = [&](u32x2& xcur, f32x4& ecur, int& mkcur,
                    const u32*& pX, const float*& pE, const int*& pM, bool rs, int par) {
        // release own write of previous step, sync, read full state
        asm volatile("s_waitcnt lgkmcnt(0)" ::: "memory");
        __builtin_amdgcn_s_barrier();
        __builtin_amdgcn_sched_barrier(0);

        const u32x4 bs0 = exchg[par][0][l];
        const u32x4 bs1 = exchg[par][1][l];
        const u32x4 bs2 = exchg[par][2][l];
        const u32x4 bs3 = exchg[par][3][l];

        f32x4 acc = {0.f, 0.f, 0.f, 0.f};
        acc = __builtin_amdgcn_mfma_f32_16x16x32_bf16(af[0], __builtin_bit_cast(bf16x8, bs0), acc, 0, 0, 0);
        acc = __builtin_amdgcn_mfma_f32_16x16x32_bf16(af[1], __builtin_bit_cast(bf16x8, bs1), acc, 0, 0, 0);
        acc = __builtin_amdgcn_mfma_f32_16x16x32_bf16(af[2], __builtin_bit_cast(bf16x8, bs2), acc, 0, 0, 0);
        acc = __builtin_amdgcn_mfma_f32_16x16x32_bf16(af[3], __builtin_bit_cast(bf16x8, bs3), acc, 0, 0, 0);

        const bool mk = (mkcur != 0);
        float sc = 1.f, klog = 0.f;
        if (rs) {   // exact pow-2 rescale; exponent of batch c's k=0 state component
            int ex = (int)((bs0[0] >> 7) & 0xFF) - 127;
            ex = __shfl(ex, c, 64);
            sc = __uint_as_float((u32)((127 - ex) & 0xFF) << 23);
            klog = (float)ex * 0.6931471805599453f;
        }

        f32x4 xf;
        if (PRE) {
            xf[0] = __uint_as_float(xcur[0] << 16);
            xf[1] = __uint_as_float(xcur[0] & 0xffff0000u);
            xf[2] = __uint_as_float(xcur[1] << 16);
            xf[3] = __uint_as_float(xcur[1] & 0xffff0000u);
        } else {
            #pragma unroll
            for (int r = 0; r < 4; ++r) xf[r] = __expf(ecur[r]);
        }

        u32 nw0, nw1;
        if (dir == 0) {  // fwd: v_t = (v@E)*x_t if mask else v
            f32x4 y;
            #pragma unroll
            for (int r = 0; r < 4; ++r) {
                float a = acc[r];
                if (rs) a *= sc;
                y[r] = a * xf[r];
            }
            nw0 = pack2bf(y[0], y[1]);
            nw1 = pack2bf(y[2], y[3]);
            nw0 = mk ? nw0 : ownprev0;
            nw1 = mk ? nw1 : ownprev1;
            ownprev0 = nw0; ownprev1 = nw1;
            if (rs && mk) Cacc += klog;
        } else {  // bwd: u = select(E@B, u); scale both branches; B = u*x_t
            f32x4 y;
            #pragma unroll
            for (int r = 0; r < 4; ++r) {
                float un = mk ? acc[r] : up[r];
                if (rs) un *= sc;
                up[r] = un;
                y[r] = un * xf[r];
            }
            nw0 = pack2bf(y[0], y[1]);
            nw1 = pack2bf(y[2], y[3]);
            if (rs) Cacc += klog;
        }

        u32* slot = reinterpret_cast<u32*>(&exchg[par ^ 1][ksw][l]) + 2*half;
        u32x2 nw2 = {nw0, nw1};
        *reinterpret_cast<u32x2*>(slot) = nw2;

        load_tile(xcur, ecur, mkcur, pX, pE, pM);
        __builtin_amdgcn_sched_barrier(0xF); // ALU/VALU/SALU/MFMA may cross; VMEM+DS pinned
    };

    load_tile(xA, eA, mkA, pXA, pEA, pMA);
    load_tile(xB, eB, mkB, pXB, pEB, pMB);
    __builtin_amdgcn_sched_barrier(0xF);

    int m = 1;
    for (; m + 3 <= M; m += 4) {       // rs static: only (m+3)%4==0 rescales; par static
        iter(xA, eA, mkA, pXA, pEA, pMA, false, 1);
        iter(xB, eB, mkB, pXB, pEB, pMB, false, 0);
        iter(xA, eA, mkA, pXA, pEA, pMA, false, 1);
        iter(xB, eB, mkB, pXB, pEB, pMB, true,  0);
    }
    for (; m <= M; ++m) {              // bwd tail m=253..255 (never a rescale step)
        if (m & 1) iter(xA, eA, mkA, pXA, pEA, pMA, false, 1);
        else       iter(xB, eB, mkB, pXB, pEB, pMB, false, 0);
    }

    // final own state: fwd from ownprev regs, bwd from f32 up
    float* vrow = vws + ((size_t)(dir*Bn + batch))*Kn + bj + 8*g;
    f32x4 fv;
    if (dir) {
        fv = up;
    } else {
        fv[0] = __uint_as_float(ownprev0 << 16);
        fv[1] = __uint_as_float(ownprev0 & 0xffff0000u);
        fv[2] = __uint_as_float(ownprev1 << 16);
        fv[3] = __uint_as_float(ownprev1 & 0xffff0000u);
    }
    *reinterpret_cast<f32x4*>(vrow) = fv;
    if (mw == 0 && g == 0) Cws[dir*Bn + batch] = Cacc;
}

// ---------------- combine: den = Cf + Cb + log(a_256 . u_256); out += num - den ----------------
__global__ void crf_combine(const float* __restrict__ vws, const float* __restrict__ Cws,
                            const float* __restrict__ num, float* __restrict__ out)
{
    const int b = blockIdx.x;
    const int tid = threadIdx.x;
    const float p = vws[(size_t)b*Kn + tid] * vws[(size_t)(Bn + b)*Kn + tid];
    __shared__ float red[128];
    red[tid] = p;
    __syncthreads();
    for (int off = 64; off > 0; off >>= 1) {
        if (tid < off) red[tid] += red[tid + off];
        __syncthreads();
    }
    if (tid == 0) {
        const float den = Cws[b] + Cws[Bn + b] + logf(red[0]);
        atomicAdd(out, num[b] - den);
    }
}

extern "C" void kernel_launch(void* const* d_in, const int* in_sizes, int n_in,
                              void* d_out, int out_size, void* d_ws, size_t ws_size,
                              hipStream_t stream)
{
    const float* em     = (const float*)d_in[0];
    const int*   tags   = (const int*)d_in[1];
    const int*   mask   = (const int*)d_in[2];
    const float* startT = (const float*)d_in[3];
    const float* endT   = (const float*)d_in[4];
    const float* trans  = (const float*)d_in[5];

    const size_t XBYTES = (size_t)Tn * Bn * Kn * 2;         // 33.5 MB
    const size_t SMALL  = 65536 + 2048 + 4096 + 524288;     // frags+num+Cws+vws
    const bool pre = (ws_size >= XBYTES + SMALL);

    char* ws = (char*)d_ws;
    u32*  X  = (u32*)ws;                                    // PRE path only
    char* base = pre ? (ws + XBYTES) : ws;
    bf16_t* frags = (bf16_t*)base;
    float*  num   = (float*)(base + 65536);
    float*  Cws   = (float*)(base + 65536 + 2048);
    float*  vws   = (float*)(base + 65536 + 2048 + 4096);
    float*  out   = (float*)d_out;

    hipLaunchKernelGGL(crf_prep, dim3(Bn + 1), dim3(128), 0, stream,
                       em, tags, mask, startT, endT, trans, frags, num, out);
    if (pre) {
        hipLaunchKernelGGL(crf_expem, dim3(4096), dim3(256), 0, stream, em, X);
        hipLaunchKernelGGL((crf_main<1>), dim3(64), dim3(512), 0, stream,
                           em, X, mask, startT, endT, frags, vws, Cws);
    } else {
        hipLaunchKernelGGL((crf_main<0>), dim3(64), dim3(512), 0, stream,
                           em, X, mask, startT, endT, frags, vws, Cws);
    }
    hipLaunchKernelGGL(crf_combine, dim3(Bn), dim3(128), 0, stream,
                       vws, Cws, num, out);
}

// Round 9
// 156.002 us; speedup vs baseline: 1.6513x; 1.0884x over previous
//
#include <hip/hip_runtime.h>
#include <hip/hip_bf16.h>

#define Tn 512
#define Bn 512
#define Kn 128

typedef __bf16 bf16_t;
typedef __bf16 bf16x8 __attribute__((ext_vector_type(8)));
typedef float f32x4 __attribute__((ext_vector_type(4)));
typedef unsigned int u32;
typedef u32 u32x2 __attribute__((ext_vector_type(2)));
typedef u32 u32x4 __attribute__((ext_vector_type(4)));

#define NEXPEM 4096   // expem blocks in fused pre-kernel

__device__ __forceinline__ u32 pack2bf(float a, float b) {
    bf16_t ha = (bf16_t)a, hb = (bf16_t)b;
    u32 ua = (u32)__builtin_bit_cast(unsigned short, ha);
    u32 ub = (u32)__builtin_bit_cast(unsigned short, hb);
    return ua | (ub << 16);
}

// ---------------- fused pre: expem (blocks 0..4095) + numerator (4096..4607)
//                  + frag build / zeroing (block 4608) ----------------
// A-frag image: idx = (((dir*8 + m)*4 + ks)*64 + l)*8 + e
//   lane roles: c=l&15, g=l>>4;  k = 32*ks + 8*g + e
//   row j = J(m,c) = 32*(m>>1) + 4*(m&1) + 8*(c>>2) + (c&3)
//   dir 0 (fwd): A[j][k] = exp(trans[k][j]);  dir 1 (bwd): A[j][k] = exp(trans[j][k])
// J chosen so D's per-lane output IS the next step's B-frag layout (verified r1-r8).
template<int PRE>
__global__ __launch_bounds__(256)
void crf_pre(const float* __restrict__ em, const int* __restrict__ tags,
             const int* __restrict__ mask, const float* __restrict__ startT,
             const float* __restrict__ endT, const float* __restrict__ trans,
             u32* __restrict__ X, bf16_t* __restrict__ frags,
             float* __restrict__ num, float* __restrict__ out, int* __restrict__ done)
{
    const int bid = blockIdx.x;
    const int tid = threadIdx.x;

    if (bid < NEXPEM) {                 // ---- expem: X = bf16(exp(em)) ----
        if (!PRE) return;
        const size_t N = (size_t)Tn * Bn * Kn;
        const size_t nth = (size_t)NEXPEM * 256;
        for (size_t base = ((size_t)bid * 256 + tid) * 8; base < N; base += nth * 8) {
            const f32x4 a = *reinterpret_cast<const f32x4*>(em + base);
            const f32x4 b = *reinterpret_cast<const f32x4*>(em + base + 4);
            u32x4 w;
            w[0] = pack2bf(__expf(a[0]), __expf(a[1]));
            w[1] = pack2bf(__expf(a[2]), __expf(a[3]));
            w[2] = pack2bf(__expf(b[0]), __expf(b[1]));
            w[3] = pack2bf(__expf(b[2]), __expf(b[3]));
            *reinterpret_cast<u32x4*>(X + base / 2) = w;
        }
        return;
    }

    const int b = bid - NEXPEM;
    if (b == Bn) {                      // ---- frags + zero out/done ----
        if (tid == 0) out[0] = 0.f;
        if (tid < 32) done[tid] = 0;
        for (int idx = tid; idx < 2*8*4*64*8; idx += blockDim.x) {
            const int e   = idx & 7;
            const int l   = (idx >> 3) & 63;
            const int ks  = (idx >> 9) & 3;
            const int m   = (idx >> 11) & 7;
            const int dir = (idx >> 14) & 1;
            const int c = l & 15, g = l >> 4;
            const int k = 32*ks + 8*g + e;
            const int j = 32*(m >> 1) + 4*(m & 1) + 8*(c >> 2) + (c & 3);
            const float v = (dir == 0) ? trans[k*Kn + j] : trans[j*Kn + k];
            frags[idx] = (bf16_t)__expf(v);
        }
        return;
    }

    // ---- numerator for batch b (256 threads) ----
    float s = 0.f;
    int cnt = 0;
    for (int t = tid; t < Tn; t += 256) {
        const int mk = mask[t*Bn + b];
        cnt += (mk != 0);
        if (t >= 1 && mk != 0) {
            const int tp = tags[(t-1)*Bn + b];
            const int tc = tags[t*Bn + b];
            s += trans[tp*Kn + tc] + em[(size_t)t*Bn*Kn + (size_t)b*Kn + tc];
        }
    }
    __shared__ float sred[256];
    __shared__ int   cred[256];
    sred[tid] = s; cred[tid] = cnt;
    __syncthreads();
    for (int off = 128; off > 0; off >>= 1) {
        if (tid < off) { sred[tid] += sred[tid+off]; cred[tid] += cred[tid+off]; }
        __syncthreads();
    }
    if (tid == 0) {
        const int t0tag = tags[b];
        const float n0 = startT[t0tag] + em[(size_t)b*Kn + t0tag];
        int seq_end = cred[0] - 1;
        if (seq_end < 0) seq_end = 0;
        const int lastTag = tags[seq_end*Bn + b];
        num[b] = n0 + sred[0] + endT[lastTag];
    }
}

// ---------------- main: 8-wave j-split recurrence + fused combine tail ----------------
// 64 blocks x 512 threads (8 waves = 2 waves/SIMD on 64 CUs). Wave mw owns m-tile mw
// (4 MFMA as 2 independent 2-chains + add), produces 4 j's/lane (u32x2 b64 write).
// State exchange: 8KB double-buffered LDS, one raw s_barrier/step. t-advance uses
// uniform (SALU) offsets + constant per-lane offsets. After the final store, the
// second-arriving block of each batch group computes the combine inline (device-scope
// done[] handshake), eliminating the separate combine kernel.
template<int PRE>
__global__ __launch_bounds__(512, 1)
void crf_main(const float* __restrict__ em, const u32* __restrict__ Xp,
              const int* __restrict__ maskp,
              const float* __restrict__ startT, const float* __restrict__ endT,
              const bf16_t* __restrict__ frags,
              float* __restrict__ vws, float* __restrict__ Cws,
              const float* __restrict__ num, float* __restrict__ out,
              int* __restrict__ done)
{
    const int bid = blockIdx.x;          // 64 blocks
    const int dir = bid & 1;
    const int grp = bid >> 1;            // batch group 0..31
    const int b0  = grp * 16;
    const int tid = threadIdx.x;
    const int mw  = tid >> 6;            // wave id = m-tile index 0..7
    const int l   = tid & 63;
    const int c = l & 15, g = l >> 4;
    const int batch = b0 + c;
    const int ksw  = mw >> 1, half = mw & 1;
    const int bj   = 32*ksw + 4*half;    // base j of own 4 outputs (plus 8g)

    __shared__ __align__(16) u32x4 exchg[2][4][64];   // [parity][slice][lane]
    __shared__ int who;

    // resident E fragments for own m-tile
    bf16x8 af[4];
    {
        const bf16_t* fb = frags + (size_t)dir * 16384;
        #pragma unroll
        for (int ks = 0; ks < 4; ++ks)
            af[ks] = *reinterpret_cast<const bf16x8*>(fb + ((mw*4 + ks)*64 + l)*8);
    }

    // init own state (+ bwd f32 state)
    f32x4 up;
    u32 ownprev0, ownprev1;
    float Cacc = 0.f;
    {
        const float* sv = dir ? endT : startT;
        const int t0 = dir ? 511 : 0;
        const f32x4 e4 = *reinterpret_cast<const f32x4*>(
            em + ((size_t)t0*Bn + batch)*Kn + bj + 8*g);
        const float* s4p = sv + bj + 8*g;
        f32x4 y;
        #pragma unroll
        for (int r = 0; r < 4; ++r) {
            const float s = s4p[r];
            y[r]  = __expf(s + e4[r]);
            up[r] = __expf(s);
        }
        ownprev0 = pack2bf(y[0], y[1]);
        ownprev1 = pack2bf(y[2], y[3]);
        u32* slot = reinterpret_cast<u32*>(&exchg[1][ksw][l]) + 2*half;
        u32x2 nw2 = {ownprev0, ownprev1};
        *reinterpret_cast<u32x2*>(slot) = nw2;   // iter m=1 reads parity 1
    }

    const int M = 256 - dir;

    // constant per-lane offsets (32-bit) + uniform t-offsets advanced on SALU
    const u32 laneX = (u32)(((batch*Kn) + bj + 8*g) >> 1);   // u32-index into X
    const u32 laneE = (u32)((batch*Kn) + bj + 8*g);          // f32-index into em
    const u32 laneM = (u32)batch;                            // int-index into mask
    const long stepX = dir ? -(long)(Bn*Kn)   : (long)(Bn*Kn);     // per 2t (u32 units)
    const long stepE = dir ? -(long)(2*Bn*Kn) : (long)(2*Bn*Kn);   // per 2t (f32 units)
    const long stepM = dir ? -(long)(2*Bn)    : (long)(2*Bn);      // per 2t (int units)
    long uXA, uXB, uEA, uEB, uMA, uMB;
    {
        const int tA  = dir ? 510 : 1, tB  = dir ? 509 : 2;
        const int tmA = dir ? 511 : 1, tmB = dir ? 510 : 2;
        uXA = (long)tA * (Bn*Kn/2);  uXB = (long)tB * (Bn*Kn/2);
        uEA = (long)tA * (Bn*Kn);    uEB = (long)tB * (Bn*Kn);
        uMA = (long)tmA * Bn;        uMB = (long)tmB * Bn;
    }

    u32x2 xA, xB; f32x4 eA, eB; int mkA, mkB;
    auto load_tile = [&](u32x2& xd, f32x4& ed, int& mk, long& uX, long& uE, long& uM) {
        if (PRE) { xd = *reinterpret_cast<const u32x2*>(Xp + uX + laneX); uX += stepX; }
        else     { ed = *reinterpret_cast<const f32x4*>(em + uE + laneE); uE += stepE; }
        mk = maskp[uM + laneM]; uM += stepM;
    };

    auto iter = [&](u32x2& xcur, f32x4& ecur, int& mkcur,
                    long& uX, long& uE, long& uM, bool rs, int par) {
        // release own write of previous step, sync, read full state
        asm volatile("s_waitcnt lgkmcnt(0)" ::: "memory");
        __builtin_amdgcn_s_barrier();
        __builtin_amdgcn_sched_barrier(0);

        const u32x4 bs0 = exchg[par][0][l];
        const u32x4 bs1 = exchg[par][1][l];
        const u32x4 bs2 = exchg[par][2][l];
        const u32x4 bs3 = exchg[par][3][l];

        // 2 independent MFMA chains of 2, then add (halves serial MFMA latency)
        f32x4 a0 = {0.f, 0.f, 0.f, 0.f}, a1 = {0.f, 0.f, 0.f, 0.f};
        a0 = __builtin_amdgcn_mfma_f32_16x16x32_bf16(af[0], __builtin_bit_cast(bf16x8, bs0), a0, 0, 0, 0);
        a1 = __builtin_amdgcn_mfma_f32_16x16x32_bf16(af[2], __builtin_bit_cast(bf16x8, bs2), a1, 0, 0, 0);
        a0 = __builtin_amdgcn_mfma_f32_16x16x32_bf16(af[1], __builtin_bit_cast(bf16x8, bs1), a0, 0, 0, 0);
        a1 = __builtin_amdgcn_mfma_f32_16x16x32_bf16(af[3], __builtin_bit_cast(bf16x8, bs3), a1, 0, 0, 0);
        const f32x4 acc = a0 + a1;

        const bool mk = (mkcur != 0);
        float sc = 1.f, klog = 0.f;
        if (rs) {   // exact pow-2 rescale; exponent of batch c's k=0 state component
            int ex = (int)((bs0[0] >> 7) & 0xFF) - 127;
            ex = __shfl(ex, c, 64);
            sc = __uint_as_float((u32)((127 - ex) & 0xFF) << 23);
            klog = (float)ex * 0.6931471805599453f;
        }

        f32x4 xf;
        if (PRE) {
            xf[0] = __uint_as_float(xcur[0] << 16);
            xf[1] = __uint_as_float(xcur[0] & 0xffff0000u);
            xf[2] = __uint_as_float(xcur[1] << 16);
            xf[3] = __uint_as_float(xcur[1] & 0xffff0000u);
        } else {
            #pragma unroll
            for (int r = 0; r < 4; ++r) xf[r] = __expf(ecur[r]);
        }

        u32 nw0, nw1;
        if (dir == 0) {  // fwd: v_t = (v@E)*x_t if mask else v
            f32x4 y;
            #pragma unroll
            for (int r = 0; r < 4; ++r) {
                float a = acc[r];
                if (rs) a *= sc;
                y[r] = a * xf[r];
            }
            nw0 = pack2bf(y[0], y[1]);
            nw1 = pack2bf(y[2], y[3]);
            nw0 = mk ? nw0 : ownprev0;
            nw1 = mk ? nw1 : ownprev1;
            ownprev0 = nw0; ownprev1 = nw1;
            if (rs && mk) Cacc += klog;
        } else {  // bwd: u = select(E@B, u); scale both branches; B = u*x_t
            f32x4 y;
            #pragma unroll
            for (int r = 0; r < 4; ++r) {
                float un = mk ? acc[r] : up[r];
                if (rs) un *= sc;
                up[r] = un;
                y[r] = un * xf[r];
            }
            nw0 = pack2bf(y[0], y[1]);
            nw1 = pack2bf(y[2], y[3]);
            if (rs) Cacc += klog;
        }

        u32* slot = reinterpret_cast<u32*>(&exchg[par ^ 1][ksw][l]) + 2*half;
        u32x2 nw2 = {nw0, nw1};
        *reinterpret_cast<u32x2*>(slot) = nw2;

        load_tile(xcur, ecur, mkcur, uX, uE, uM);
        __builtin_amdgcn_sched_barrier(0xF); // ALU/VALU/SALU/MFMA may cross; VMEM+DS pinned
    };

    load_tile(xA, eA, mkA, uXA, uEA, uMA);
    load_tile(xB, eB, mkB, uXB, uEB, uMB);
    __builtin_amdgcn_sched_barrier(0xF);

    int m = 1;
    for (; m + 3 <= M; m += 4) {       // rs static: only (m+3)%4==0 rescales; par static
        iter(xA, eA, mkA, uXA, uEA, uMA, false, 1);
        iter(xB, eB, mkB, uXB, uEB, uMB, false, 0);
        iter(xA, eA, mkA, uXA, uEA, uMA, false, 1);
        iter(xB, eB, mkB, uXB, uEB, uMB, true,  0);
    }
    for (; m <= M; ++m) {              // bwd tail m=253..255 (never a rescale step)
        if (m & 1) iter(xA, eA, mkA, uXA, uEA, uMA, false, 1);
        else       iter(xB, eB, mkB, uXB, uEB, uMB, false, 0);
    }

    // final own state: fwd from ownprev regs, bwd from f32 up
    float* vrow = vws + ((size_t)(dir*Bn + batch))*Kn + bj + 8*g;
    f32x4 fv;
    if (dir) {
        fv = up;
    } else {
        fv[0] = __uint_as_float(ownprev0 << 16);
        fv[1] = __uint_as_float(ownprev0 & 0xffff0000u);
        fv[2] = __uint_as_float(ownprev1 << 16);
        fv[3] = __uint_as_float(ownprev1 & 0xffff0000u);
    }
    *reinterpret_cast<f32x4*>(vrow) = fv;
    if (mw == 0 && g == 0) Cws[dir*Bn + batch] = Cacc;

    // ---- fused combine: second-arriving block of this group does it ----
    __threadfence();                       // release vws/Cws stores
    if (tid == 0) who = atomicAdd(&done[grp], 1);
    __syncthreads();
    if (who == 1) {
        __threadfence();                   // acquire other block's stores
        const int cb   = tid >> 5;         // batch within group 0..15
        const int part = tid & 31;
        const float* vf = vws + (size_t)(b0 + cb)*Kn;
        const float* vu = vws + (size_t)(Bn + b0 + cb)*Kn;
        float s = 0.f;
        #pragma unroll
        for (int r = 0; r < 4; ++r) {
            const int k = part*4 + r;
            s += vf[k] * vu[k];
        }
        #pragma unroll
        for (int o = 16; o > 0; o >>= 1) s += __shfl_xor(s, o, 32);
        if (part == 0) {
            const float den = Cws[b0 + cb] + Cws[Bn + b0 + cb] + logf(s);
            atomicAdd(out, num[b0 + cb] - den);
        }
    }
}

extern "C" void kernel_launch(void* const* d_in, const int* in_sizes, int n_in,
                              void* d_out, int out_size, void* d_ws, size_t ws_size,
                              hipStream_t stream)
{
    const float* em     = (const float*)d_in[0];
    const int*   tags   = (const int*)d_in[1];
    const int*   mask   = (const int*)d_in[2];
    const float* startT = (const float*)d_in[3];
    const float* endT   = (const float*)d_in[4];
    const float* trans  = (const float*)d_in[5];

    const size_t XBYTES = (size_t)Tn * Bn * Kn * 2;               // 33.5 MB
    const size_t SMALL  = 65536 + 2048 + 4096 + 524288 + 256;     // frags+num+Cws+vws+done
    const bool pre = (ws_size >= XBYTES + SMALL);

    char* ws = (char*)d_ws;
    u32*  X  = (u32*)ws;                                    // PRE path only
    char* base = pre ? (ws + XBYTES) : ws;
    bf16_t* frags = (bf16_t*)base;
    float*  num   = (float*)(base + 65536);
    float*  Cws   = (float*)(base + 65536 + 2048);
    float*  vws   = (float*)(base + 65536 + 2048 + 4096);
    int*    done  = (int*)(base + 65536 + 2048 + 4096 + 524288);
    float*  out   = (float*)d_out;

    if (pre) {
        hipLaunchKernelGGL((crf_pre<1>), dim3(NEXPEM + Bn + 1), dim3(256), 0, stream,
                           em, tags, mask, startT, endT, trans, X, frags, num, out, done);
        hipLaunchKernelGGL((crf_main<1>), dim3(64), dim3(512), 0, stream,
                           em, X, mask, startT, endT, frags, vws, Cws, num, out, done);
    } else {
        hipLaunchKernelGGL((crf_pre<0>), dim3(NEXPEM + Bn + 1), dim3(256), 0, stream,
                           em, tags, mask, startT, endT, trans, X, frags, num, out, done);
        hipLaunchKernelGGL((crf_main<0>), dim3(64), dim3(512), 0, stream,
                           em, X, mask, startT, endT, frags, vws, Cws, num, out, done);
    }
}